// Round 6
// baseline (888.536 us; speedup 1.0000x reference)
//
#include <hip/hip_runtime.h>
#include <hip/hip_fp16.h>

#define IN_DIM 128
#define OUT_DIM 64
#define RPB 256          // rows per bucket (LDS accumulator: 256x64 f32 = 64 KB)
#define MAXB 400         // max buckets  (n_nodes <= 102400)
#define EPB 2048         // edges per block in k_pre/k_fill (512 thr x 4)

typedef __attribute__((ext_vector_type(8))) _Float16 half8;
typedef __attribute__((ext_vector_type(4))) float f32x4;

// Phase 1 (MFMA): wh = h @ w_w + w_b (stored fp16); s_row = wh@a1; s_col = wh@a2.
__global__ __launch_bounds__(256) void k_wh(
    const float* __restrict__ h, const float* __restrict__ w_w,
    const float* __restrict__ w_b, const float* __restrict__ a_w,
    __half* __restrict__ wh, float* __restrict__ s_row,
    float* __restrict__ s_col, int n_nodes) {
  __shared__ _Float16 wf[4 * 4 * 64 * 8];
  for (int idx = threadIdx.x; idx < IN_DIM * OUT_DIM; idx += 256) {
    int k = idx >> 6, c = idx & 63;            // w_w[k][c], coalesced read
    int mt = c >> 4;
    int kt = k >> 5;
    int l = (((k >> 3) & 3) << 4) | (c & 15);  // lane that owns this (k,c)
    int j = k & 7;
    wf[(((mt << 2) | kt) << 9) | (l << 3) | j] = (_Float16)w_w[idx];
  }
  __syncthreads();

  const int lane = threadIdx.x & 63;
  const int wv = threadIdx.x >> 6;

  half8 A[4][4];
#pragma unroll
  for (int mt = 0; mt < 4; ++mt)
#pragma unroll
    for (int kt = 0; kt < 4; ++kt)
      A[mt][kt] =
          *(const half8*)&wf[(((mt << 2) | kt) << 9) | (lane << 3)];

  const int cbase = (lane >> 4) << 2;
  f32x4 bq[4], a1q[4], a2q[4];
#pragma unroll
  for (int mt = 0; mt < 4; ++mt) {
    bq[mt] = *(const f32x4*)&w_b[mt * 16 + cbase];
    a1q[mt] = *(const f32x4*)&a_w[mt * 16 + cbase];
    a2q[mt] = *(const f32x4*)&a_w[OUT_DIM + mt * 16 + cbase];
  }

  const int ntiles = (n_nodes + 15) >> 4;
  const int tstride = gridDim.x << 2;
  for (int t = blockIdx.x * 4 + wv; t < ntiles; t += tstride) {
    const int n0 = t << 4;
    const int node = n0 + (lane & 15);
    const int nodec = node < n_nodes ? node : n_nodes - 1;
    const float4* hv =
        (const float4*)(h + (size_t)nodec * IN_DIM + ((lane >> 4) << 3));
    float4 p[8];
#pragma unroll
    for (int kt = 0; kt < 4; ++kt) {
      p[2 * kt] = hv[kt * 8];
      p[2 * kt + 1] = hv[kt * 8 + 1];
    }
    f32x4 C[4];
#pragma unroll
    for (int mt = 0; mt < 4; ++mt) C[mt] = (f32x4){0.f, 0.f, 0.f, 0.f};
#pragma unroll
    for (int kt = 0; kt < 4; ++kt) {
      const float4 u = p[2 * kt], v = p[2 * kt + 1];
      half8 B;
      B[0] = (_Float16)u.x; B[1] = (_Float16)u.y;
      B[2] = (_Float16)u.z; B[3] = (_Float16)u.w;
      B[4] = (_Float16)v.x; B[5] = (_Float16)v.y;
      B[6] = (_Float16)v.z; B[7] = (_Float16)v.w;
#pragma unroll
      for (int mt = 0; mt < 4; ++mt)
        C[mt] = __builtin_amdgcn_mfma_f32_16x16x32_f16(A[mt][kt], B, C[mt],
                                                       0, 0, 0);
    }
    float sr = 0.f, sc = 0.f;
    uint2 q[4];
#pragma unroll
    for (int mt = 0; mt < 4; ++mt) {
      f32x4 d = C[mt] + bq[mt];
      sr += d[0] * a1q[mt][0] + d[1] * a1q[mt][1] + d[2] * a1q[mt][2] +
            d[3] * a1q[mt][3];
      sc += d[0] * a2q[mt][0] + d[1] * a2q[mt][1] + d[2] * a2q[mt][2] +
            d[3] * a2q[mt][3];
      __half2 lo = __floats2half2_rn(d[0], d[1]);
      __half2 hi = __floats2half2_rn(d[2], d[3]);
      q[mt].x = *(unsigned int*)&lo;
      q[mt].y = *(unsigned int*)&hi;
    }
    if (node < n_nodes) {
      uint2* wrow = (uint2*)(wh + (size_t)node * OUT_DIM + cbase);
      wrow[0] = q[0];
      wrow[4] = q[1];
      wrow[8] = q[2];
      wrow[12] = q[3];
    }
    sr += __shfl_xor(sr, 16, 64);
    sr += __shfl_xor(sr, 32, 64);
    sc += __shfl_xor(sc, 16, 64);
    sc += __shfl_xor(sc, 32, 64);
    if (lane < 16 && node < n_nodes) {
      s_row[node] = sr;
      s_col[node] = sc;
    }
  }
}

// Per-block bucket histogram (bucket = row >> 8, RPB=256).
__global__ __launch_bounds__(512) void k_pre(
    const int* __restrict__ ei, int* __restrict__ blockhist, int nedges) {
  __shared__ int hist[MAXB];
  for (int b = threadIdx.x; b < MAXB; b += 512) hist[b] = 0;
  __syncthreads();
  const int e0 = blockIdx.x * EPB;
  if (e0 + EPB <= nedges) {
    const int e = e0 + threadIdx.x;
    int r0 = ei[e];
    int r1 = ei[e + 512];
    int r2 = ei[e + 1024];
    int r3 = ei[e + 1536];
    atomicAdd(&hist[r0 >> 8], 1);
    atomicAdd(&hist[r1 >> 8], 1);
    atomicAdd(&hist[r2 >> 8], 1);
    atomicAdd(&hist[r3 >> 8], 1);
  } else {
#pragma unroll
    for (int r = 0; r < EPB / 512; ++r) {
      int e = e0 + r * 512 + threadIdx.x;
      if (e < nedges) atomicAdd(&hist[ei[e] >> 8], 1);
    }
  }
  __syncthreads();
  for (int b = threadIdx.x; b < MAXB; b += 512)
    blockhist[blockIdx.x * MAXB + b] = hist[b];
}

// Per-bucket exclusive scan over up to 1024 blocks of LINE-PADDED counts
// (roundup 8 entries = 64B): every (block,bucket) run starts line-aligned.
__global__ __launch_bounds__(512) void k_scanA(
    const int* __restrict__ blockhist, int* __restrict__ boff,
    int* __restrict__ cnt, int nbl) {
  __shared__ int sd[512];
  const int b = blockIdx.x, t = threadIdx.x;
  int i0 = 2 * t, i1 = 2 * t + 1;
  int v0 = (i0 < nbl) ? ((blockhist[i0 * MAXB + b] + 7) & ~7) : 0;
  int v1 = (i1 < nbl) ? ((blockhist[i1 * MAXB + b] + 7) & ~7) : 0;
  int ts = v0 + v1;
  sd[t] = ts;
  __syncthreads();
  for (int off = 1; off < 512; off <<= 1) {
    int x = (t >= off) ? sd[t - off] : 0;
    __syncthreads();
    sd[t] += x;
    __syncthreads();
  }
  int excl = sd[t] - ts;
  if (i0 < nbl) boff[i0 * MAXB + b] = excl;
  if (i1 < nbl) boff[i1 * MAXB + b] = excl + v0;
  if (t == 511) cnt[b] = sd[511];  // padded bucket total (multiple of 8)
}

// Exclusive scan of 128B-padded bucket counts -> bucket bases (nb <= 512).
__global__ __launch_bounds__(512) void k_scanB(
    const int* __restrict__ cnt, int* __restrict__ bbase, int nb) {
  __shared__ int sd[512];
  int t = threadIdx.x;
  int pc = (t < nb) ? ((cnt[t] + 15) & ~15) : 0;
  sd[t] = pc;
  __syncthreads();
  for (int off = 1; off < 512; off <<= 1) {
    int x = (t >= off) ? sd[t - off] : 0;
    __syncthreads();
    sd[t] += x;
    __syncthreads();
  }
  if (t < nb) bbase[t] = sd[t] - pc;
}

// Phase 2: NO random gathers. Pure coalesced streams (ei, edge_attr) ->
// ea3 = edge_attr@a3 -> deterministic line-aligned bucket-grouped scatter.
// Entry: x = ((row&255)<<17)|col, y = ea3. Tails padded with x=-1.
__global__ __launch_bounds__(512) void k_fill(
    const int* __restrict__ ei, const float* __restrict__ edge_attr,
    const float* __restrict__ a_w,
    const int* __restrict__ boff, const int* __restrict__ bbase,
    int2* __restrict__ entA, int nedges, int nb) {
  __shared__ int cur[MAXB];
  for (int b = threadIdx.x; b < MAXB; b += 512)
    cur[b] = (b < nb) ? bbase[b] + boff[blockIdx.x * MAXB + b] : 0;
  float aw0 = a_w[128], aw1 = a_w[129], aw2 = a_w[130], aw3 = a_w[131];
  float aw4 = a_w[132], aw5 = a_w[133], aw6 = a_w[134], aw7 = a_w[135];
  __syncthreads();
  const int e0 = blockIdx.x * EPB;
  if (e0 + EPB <= nedges) {
    const int e = e0 + threadIdx.x;
    int row[4], col[4];
#pragma unroll
    for (int r = 0; r < 4; ++r) {
      row[r] = ei[e + r * 512];
      col[r] = ei[nedges + e + r * 512];
    }
    float4 u[4], v[4];
#pragma unroll
    for (int r = 0; r < 4; ++r) {
      const float4* ea = (const float4*)(edge_attr + (size_t)(e + r * 512) * 8);
      u[r] = ea[0];
      v[r] = ea[1];
    }
#pragma unroll
    for (int r = 0; r < 4; ++r) {
      float s = u[r].x * aw0 + u[r].y * aw1 + u[r].z * aw2 + u[r].w * aw3;
      s += v[r].x * aw4 + v[r].y * aw5 + v[r].z * aw6 + v[r].w * aw7;
      int pos = atomicAdd(&cur[row[r] >> 8], 1);
      entA[pos] =
          make_int2(((row[r] & 255) << 17) | col[r], __float_as_int(s));
    }
  } else {
    for (int r = 0; r < EPB / 512; ++r) {
      int e = e0 + r * 512 + threadIdx.x;
      if (e < nedges) {
        int row = ei[e];
        int col = ei[nedges + e];
        const float4* ea = (const float4*)(edge_attr + (size_t)e * 8);
        float4 u = ea[0], v = ea[1];
        float s = u.x * aw0 + u.y * aw1 + u.z * aw2 + u.w * aw3;
        s += v.x * aw4 + v.y * aw5 + v.z * aw6 + v.w * aw7;
        int pos = atomicAdd(&cur[row >> 8], 1);
        entA[pos] = make_int2(((row & 255) << 17) | col, __float_as_int(s));
      }
    }
  }
  __syncthreads();
  // pad each run's tail to its 64B line end with sentinels
  for (int b = threadIdx.x; b < nb; b += 512) {
    int c = cur[b], end = (c + 7) & ~7;
    for (int k = c; k < end; ++k) entA[k] = make_int2(-1, 0);
  }
}

// Phase 3 (fused sort+agg): one block per bucket; 256x64 fp32 accumulator
// in LDS with (row&3)*8 dim-rotation (breaks 8-way bank aliasing on
// ds_add_f32). Streams bucket entries (sentinel-skip), gathers wh[col]
// (8 lanes x 16B) + s_col[col], finishes score, exp, LDS atomic accumulate.
// Then normalized coalesced writeout. No CSR, no counting sort, no entB.
__global__ __launch_bounds__(1024) void k_edge(
    const int2* __restrict__ entA, const int* __restrict__ cnt,
    const int* __restrict__ bbase, const __half* __restrict__ wh,
    const float* __restrict__ s_row, const float* __restrict__ s_col,
    const float* __restrict__ a_b, float* __restrict__ out, int n_nodes) {
  __shared__ float acc[RPB * 64];  // 64 KB, rotated dims
  __shared__ float nrm[RPB];
  __shared__ float sr[RPB];
  const int b = blockIdx.x;
  const int row0 = b << 8;
  const int t = threadIdx.x;
  for (int i = t; i < RPB * 64; i += 1024) acc[i] = 0.f;
  if (t < RPB) {
    nrm[t] = 0.f;
    int node = row0 + t;
    sr[t] = (node < n_nodes) ? s_row[node] : 0.f;
  }
  __syncthreads();
  const int c = __builtin_amdgcn_readfirstlane(cnt[b]);     // padded count
  const int base = __builtin_amdgcn_readfirstlane(bbase[b]);
  const float ab = a_b[0];
  const int slot = t >> 3;   // 0..127
  const int sub = t & 7;
  const uint4* whq = (const uint4*)wh;
  for (int i = slot; i < c; i += 256) {
    const int i1 = i + 128;
    int2 p0 = entA[base + i];
    int2 p1 = (i1 < c) ? entA[base + i1] : make_int2(-1, 0);
    const bool g0 = p0.x >= 0, g1 = p1.x >= 0;
    int col0 = p0.x & 0x1FFFF, col1 = p1.x & 0x1FFFF;
    uint4 q0 = make_uint4(0, 0, 0, 0), q1 = make_uint4(0, 0, 0, 0);
    float sc0 = 0.f, sc1 = 0.f;
    if (g0) { q0 = whq[(size_t)col0 * 8 + sub]; sc0 = s_col[col0]; }
    if (g1) { q1 = whq[(size_t)col1 * 8 + sub]; sc1 = s_col[col1]; }
    if (g0) {
      int rl = p0.x >> 17;
      float s = sr[rl] + sc0 + __int_as_float(p0.y) + ab;
      float ev = (s > 0.f) ? s : 0.01f * s;  // leaky_relu
      float a = __expf(ev);  // softmax shift-invariance: no segment max
      float2 f0 = __half22float2(*(__half2*)&q0.x);
      float2 f1 = __half22float2(*(__half2*)&q0.y);
      float2 f2 = __half22float2(*(__half2*)&q0.z);
      float2 f3 = __half22float2(*(__half2*)&q0.w);
      const int rb = rl << 6, rot = (rl & 3) << 3, d = sub << 3;
      atomicAdd(&acc[rb + ((d + 0 + rot) & 63)], a * f0.x);
      atomicAdd(&acc[rb + ((d + 1 + rot) & 63)], a * f0.y);
      atomicAdd(&acc[rb + ((d + 2 + rot) & 63)], a * f1.x);
      atomicAdd(&acc[rb + ((d + 3 + rot) & 63)], a * f1.y);
      atomicAdd(&acc[rb + ((d + 4 + rot) & 63)], a * f2.x);
      atomicAdd(&acc[rb + ((d + 5 + rot) & 63)], a * f2.y);
      atomicAdd(&acc[rb + ((d + 6 + rot) & 63)], a * f3.x);
      atomicAdd(&acc[rb + ((d + 7 + rot) & 63)], a * f3.y);
      if (sub == 0) atomicAdd(&nrm[rl], a);
    }
    if (g1) {
      int rl = p1.x >> 17;
      float s = sr[rl] + sc1 + __int_as_float(p1.y) + ab;
      float ev = (s > 0.f) ? s : 0.01f * s;
      float a = __expf(ev);
      float2 f0 = __half22float2(*(__half2*)&q1.x);
      float2 f1 = __half22float2(*(__half2*)&q1.y);
      float2 f2 = __half22float2(*(__half2*)&q1.z);
      float2 f3 = __half22float2(*(__half2*)&q1.w);
      const int rb = rl << 6, rot = (rl & 3) << 3, d = sub << 3;
      atomicAdd(&acc[rb + ((d + 0 + rot) & 63)], a * f0.x);
      atomicAdd(&acc[rb + ((d + 1 + rot) & 63)], a * f0.y);
      atomicAdd(&acc[rb + ((d + 2 + rot) & 63)], a * f1.x);
      atomicAdd(&acc[rb + ((d + 3 + rot) & 63)], a * f1.y);
      atomicAdd(&acc[rb + ((d + 4 + rot) & 63)], a * f2.x);
      atomicAdd(&acc[rb + ((d + 5 + rot) & 63)], a * f2.y);
      atomicAdd(&acc[rb + ((d + 6 + rot) & 63)], a * f3.x);
      atomicAdd(&acc[rb + ((d + 7 + rot) & 63)], a * f3.y);
      if (sub == 0) atomicAdd(&nrm[rl], a);
    }
  }
  __syncthreads();
  // writeout: RPB rows x 16 float4 = 4096 float4
  for (int idx = t; idx < RPB * 16; idx += 1024) {
    const int row = idx >> 4;
    const int node = row0 + row;
    if (node < n_nodes) {
      const int d0 = (idx & 15) << 2;
      const int rb = row << 6, rot = (row & 3) << 3;
      const float inv = 1.0f / (nrm[row] + 1e-8f);
      float4 o;
      o.x = acc[rb + ((d0 + 0 + rot) & 63)] * inv;
      o.y = acc[rb + ((d0 + 1 + rot) & 63)] * inv;
      o.z = acc[rb + ((d0 + 2 + rot) & 63)] * inv;
      o.w = acc[rb + ((d0 + 3 + rot) & 63)] * inv;
      ((float4*)out)[(size_t)node * 16 + (idx & 15)] = o;
    }
  }
}

extern "C" void kernel_launch(void* const* d_in, const int* in_sizes, int n_in,
                              void* d_out, int out_size, void* d_ws, size_t ws_size,
                              hipStream_t stream) {
  const float* h         = (const float*)d_in[0];
  const int*   ei        = (const int*)d_in[1];
  const float* edge_attr = (const float*)d_in[2];
  const float* w_w       = (const float*)d_in[3];
  const float* w_b       = (const float*)d_in[4];
  const float* a_w       = (const float*)d_in[5];
  const float* a_b       = (const float*)d_in[6];
  const int n_nodes = in_sizes[0] / IN_DIM;
  const int nedges  = in_sizes[1] / 2;
  const int nb   = (n_nodes + RPB - 1) / RPB;   // 391
  const int nebl = (nedges + EPB - 1) / EPB;    // 782

  // entA capacity with line padding: nedges + nebl*nb*8 + nb*16
  const size_t entcap = (size_t)nedges + (size_t)nebl * nb * 8 + (size_t)nb * 16;

  // Workspace (~49 MB):
  __half* wh       = (__half*)d_ws;                           // n*64 fp16
  int2*  entA      = (int2*)(wh + (size_t)n_nodes * OUT_DIM); // entcap
  int*   cnt       = (int*)(entA + entcap);                   // MAXB
  int*   bbase     = cnt + MAXB;                              // MAXB
  float* s_row     = (float*)(bbase + MAXB);                  // n
  float* s_col     = s_row + n_nodes;                         // n
  int*   blockhist = (int*)(s_col + n_nodes);                 // nebl*MAXB
  int*   boff      = blockhist + (size_t)nebl * MAXB;         // nebl*MAXB

  k_wh<<<640, 256, 0, stream>>>(h, w_w, w_b, a_w, wh, s_row, s_col, n_nodes);
  k_pre<<<nebl, 512, 0, stream>>>(ei, blockhist, nedges);
  k_scanA<<<nb, 512, 0, stream>>>(blockhist, boff, cnt, nebl);
  k_scanB<<<1, 512, 0, stream>>>(cnt, bbase, nb);
  k_fill<<<nebl, 512, 0, stream>>>(ei, edge_attr, a_w, boff, bbase, entA,
                                   nedges, nb);
  k_edge<<<nb, 1024, 0, stream>>>(entA, cnt, bbase, wh, s_row, s_col, a_b,
                                  (float*)d_out, n_nodes);
}

// Round 7
// 255.427 us; speedup vs baseline: 3.4786x; 3.4786x over previous
//
#include <hip/hip_runtime.h>
#include <hip/hip_fp16.h>

#define IN_DIM 128
#define OUT_DIM 64
#define RPB 128          // rows per bucket (in-LDS sort+agg)
#define MAXB 800         // max buckets  (n_nodes <= 102400)
#define EPB 4096         // edges per block in k_pre/k_fill (512 thr x 8)
#define ENTL 2304        // LDS entry cap per bucket (mean 2048 + >5 sigma)

typedef __attribute__((ext_vector_type(8))) _Float16 half8;
typedef __attribute__((ext_vector_type(4))) float f32x4;

// Phase 1 (MFMA): wh = h @ w_w + w_b (stored fp16); s_row = wh@a1; s_col = wh@a2.
__global__ __launch_bounds__(256) void k_wh(
    const float* __restrict__ h, const float* __restrict__ w_w,
    const float* __restrict__ w_b, const float* __restrict__ a_w,
    __half* __restrict__ wh, float* __restrict__ s_row,
    float* __restrict__ s_col, int n_nodes) {
  __shared__ _Float16 wf[4 * 4 * 64 * 8];
  for (int idx = threadIdx.x; idx < IN_DIM * OUT_DIM; idx += 256) {
    int k = idx >> 6, c = idx & 63;            // w_w[k][c], coalesced read
    int mt = c >> 4;
    int kt = k >> 5;
    int l = (((k >> 3) & 3) << 4) | (c & 15);  // lane that owns this (k,c)
    int j = k & 7;
    wf[(((mt << 2) | kt) << 9) | (l << 3) | j] = (_Float16)w_w[idx];
  }
  __syncthreads();

  const int lane = threadIdx.x & 63;
  const int wv = threadIdx.x >> 6;

  half8 A[4][4];
#pragma unroll
  for (int mt = 0; mt < 4; ++mt)
#pragma unroll
    for (int kt = 0; kt < 4; ++kt)
      A[mt][kt] =
          *(const half8*)&wf[(((mt << 2) | kt) << 9) | (lane << 3)];

  const int cbase = (lane >> 4) << 2;
  f32x4 bq[4], a1q[4], a2q[4];
#pragma unroll
  for (int mt = 0; mt < 4; ++mt) {
    bq[mt] = *(const f32x4*)&w_b[mt * 16 + cbase];
    a1q[mt] = *(const f32x4*)&a_w[mt * 16 + cbase];
    a2q[mt] = *(const f32x4*)&a_w[OUT_DIM + mt * 16 + cbase];
  }

  const int ntiles = (n_nodes + 15) >> 4;
  const int tstride = gridDim.x << 2;
  for (int t = blockIdx.x * 4 + wv; t < ntiles; t += tstride) {
    const int n0 = t << 4;
    const int node = n0 + (lane & 15);
    const int nodec = node < n_nodes ? node : n_nodes - 1;
    const float4* hv =
        (const float4*)(h + (size_t)nodec * IN_DIM + ((lane >> 4) << 3));
    float4 p[8];
#pragma unroll
    for (int kt = 0; kt < 4; ++kt) {
      p[2 * kt] = hv[kt * 8];
      p[2 * kt + 1] = hv[kt * 8 + 1];
    }
    f32x4 C[4];
#pragma unroll
    for (int mt = 0; mt < 4; ++mt) C[mt] = (f32x4){0.f, 0.f, 0.f, 0.f};
#pragma unroll
    for (int kt = 0; kt < 4; ++kt) {
      const float4 u = p[2 * kt], v = p[2 * kt + 1];
      half8 B;
      B[0] = (_Float16)u.x; B[1] = (_Float16)u.y;
      B[2] = (_Float16)u.z; B[3] = (_Float16)u.w;
      B[4] = (_Float16)v.x; B[5] = (_Float16)v.y;
      B[6] = (_Float16)v.z; B[7] = (_Float16)v.w;
#pragma unroll
      for (int mt = 0; mt < 4; ++mt)
        C[mt] = __builtin_amdgcn_mfma_f32_16x16x32_f16(A[mt][kt], B, C[mt],
                                                       0, 0, 0);
    }
    float sr = 0.f, sc = 0.f;
    uint2 q[4];
#pragma unroll
    for (int mt = 0; mt < 4; ++mt) {
      f32x4 d = C[mt] + bq[mt];
      sr += d[0] * a1q[mt][0] + d[1] * a1q[mt][1] + d[2] * a1q[mt][2] +
            d[3] * a1q[mt][3];
      sc += d[0] * a2q[mt][0] + d[1] * a2q[mt][1] + d[2] * a2q[mt][2] +
            d[3] * a2q[mt][3];
      __half2 lo = __floats2half2_rn(d[0], d[1]);
      __half2 hi = __floats2half2_rn(d[2], d[3]);
      q[mt].x = *(unsigned int*)&lo;
      q[mt].y = *(unsigned int*)&hi;
    }
    if (node < n_nodes) {
      uint2* wrow = (uint2*)(wh + (size_t)node * OUT_DIM + cbase);
      wrow[0] = q[0];
      wrow[4] = q[1];
      wrow[8] = q[2];
      wrow[12] = q[3];
    }
    sr += __shfl_xor(sr, 16, 64);
    sr += __shfl_xor(sr, 32, 64);
    sc += __shfl_xor(sc, 16, 64);
    sc += __shfl_xor(sc, 32, 64);
    if (lane < 16 && node < n_nodes) {
      s_row[node] = sr;
      s_col[node] = sc;
    }
  }
}

// Per-block bucket histogram (bucket = row >> 7, RPB=128).
__global__ __launch_bounds__(512) void k_pre(
    const int* __restrict__ ei, int* __restrict__ blockhist, int nedges) {
  __shared__ int hist[MAXB];
  for (int b = threadIdx.x; b < MAXB; b += 512) hist[b] = 0;
  __syncthreads();
  const int e0 = blockIdx.x * EPB;
  if (e0 + EPB <= nedges) {
    const int e = e0 + threadIdx.x;
    int r[8];
#pragma unroll
    for (int k = 0; k < 8; ++k) r[k] = ei[e + k * 512];
#pragma unroll
    for (int k = 0; k < 8; ++k) atomicAdd(&hist[r[k] >> 7], 1);
  } else {
#pragma unroll
    for (int k = 0; k < 8; ++k) {
      int e = e0 + k * 512 + threadIdx.x;
      if (e < nedges) atomicAdd(&hist[ei[e] >> 7], 1);
    }
  }
  __syncthreads();
  for (int b = threadIdx.x; b < MAXB; b += 512)
    blockhist[blockIdx.x * MAXB + b] = hist[b];
}

// Per-bucket exclusive scan over up to 1024 blocks of LINE-PADDED counts
// (roundup 8 entries = 64B): every (block,bucket) run starts line-aligned.
__global__ __launch_bounds__(512) void k_scanA(
    const int* __restrict__ blockhist, int* __restrict__ boff,
    int* __restrict__ cnt, int nbl) {
  __shared__ int sd[512];
  const int b = blockIdx.x, t = threadIdx.x;
  int i0 = 2 * t, i1 = 2 * t + 1;
  int v0 = (i0 < nbl) ? ((blockhist[i0 * MAXB + b] + 7) & ~7) : 0;
  int v1 = (i1 < nbl) ? ((blockhist[i1 * MAXB + b] + 7) & ~7) : 0;
  int ts = v0 + v1;
  sd[t] = ts;
  __syncthreads();
  for (int off = 1; off < 512; off <<= 1) {
    int x = (t >= off) ? sd[t - off] : 0;
    __syncthreads();
    sd[t] += x;
    __syncthreads();
  }
  int excl = sd[t] - ts;
  if (i0 < nbl) boff[i0 * MAXB + b] = excl;
  if (i1 < nbl) boff[i1 * MAXB + b] = excl + v0;
  if (t == 511) cnt[b] = sd[511];  // padded bucket total (multiple of 8)
}

// Exclusive scan of 128B-padded bucket counts -> bucket bases (nb <= 1024).
__global__ __launch_bounds__(512) void k_scanB(
    const int* __restrict__ cnt, int* __restrict__ bbase, int nb) {
  __shared__ int sd[512];
  int t = threadIdx.x;
  int i0 = 2 * t, i1 = 2 * t + 1;
  int v0 = (i0 < nb) ? ((cnt[i0] + 15) & ~15) : 0;
  int v1 = (i1 < nb) ? ((cnt[i1] + 15) & ~15) : 0;
  int ts = v0 + v1;
  sd[t] = ts;
  __syncthreads();
  for (int off = 1; off < 512; off <<= 1) {
    int x = (t >= off) ? sd[t - off] : 0;
    __syncthreads();
    sd[t] += x;
    __syncthreads();
  }
  int excl = sd[t] - ts;
  if (i0 < nb) bbase[i0] = excl;
  if (i1 < nb) bbase[i1] = excl + v0;
}

// Phase 2: NO random gathers. Pure coalesced streams (ei, edge_attr) ->
// ea3 = edge_attr@a3 -> deterministic line-aligned bucket-grouped scatter.
// Entry: x = ((row&127)<<17)|col, y = ea3. Tails padded with x=-1.
__global__ __launch_bounds__(512) void k_fill(
    const int* __restrict__ ei, const float* __restrict__ edge_attr,
    const float* __restrict__ a_w,
    const int* __restrict__ boff, const int* __restrict__ bbase,
    int2* __restrict__ entA, int nedges, int nb) {
  __shared__ int cur[MAXB];
  for (int b = threadIdx.x; b < MAXB; b += 512)
    cur[b] = (b < nb) ? bbase[b] + boff[blockIdx.x * MAXB + b] : 0;
  float aw0 = a_w[128], aw1 = a_w[129], aw2 = a_w[130], aw3 = a_w[131];
  float aw4 = a_w[132], aw5 = a_w[133], aw6 = a_w[134], aw7 = a_w[135];
  __syncthreads();
  const int e0 = blockIdx.x * EPB;
  if (e0 + EPB <= nedges) {
#pragma unroll
    for (int g = 0; g < 2; ++g) {
      const int e = e0 + g * 2048 + threadIdx.x;
      int row[4], col[4];
#pragma unroll
      for (int r = 0; r < 4; ++r) {
        row[r] = ei[e + r * 512];
        col[r] = ei[nedges + e + r * 512];
      }
      float4 u[4], v[4];
#pragma unroll
      for (int r = 0; r < 4; ++r) {
        const float4* ea =
            (const float4*)(edge_attr + (size_t)(e + r * 512) * 8);
        u[r] = ea[0];
        v[r] = ea[1];
      }
#pragma unroll
      for (int r = 0; r < 4; ++r) {
        float s = u[r].x * aw0 + u[r].y * aw1 + u[r].z * aw2 + u[r].w * aw3;
        s += v[r].x * aw4 + v[r].y * aw5 + v[r].z * aw6 + v[r].w * aw7;
        int pos = atomicAdd(&cur[row[r] >> 7], 1);
        entA[pos] =
            make_int2(((row[r] & 127) << 17) | col[r], __float_as_int(s));
      }
    }
  } else {
    for (int k = 0; k < 8; ++k) {
      int e = e0 + k * 512 + threadIdx.x;
      if (e < nedges) {
        int row = ei[e];
        int col = ei[nedges + e];
        const float4* ea = (const float4*)(edge_attr + (size_t)e * 8);
        float4 u = ea[0], v = ea[1];
        float s = u.x * aw0 + u.y * aw1 + u.z * aw2 + u.w * aw3;
        s += v.x * aw4 + v.y * aw5 + v.z * aw6 + v.w * aw7;
        int pos = atomicAdd(&cur[row >> 7], 1);
        entA[pos] = make_int2(((row & 127) << 17) | col, __float_as_int(s));
      }
    }
  }
  __syncthreads();
  // pad each run's tail to its 64B line end with sentinels
  for (int b = threadIdx.x; b < nb; b += 512) {
    int c = cur[b], end = (c + 7) & ~7;
    for (int k = c; k < end; ++k) entA[k] = make_int2(-1, 0);
  }
}

// Phase 3 (fused sort+agg, NO LDS-atomic accumulators): one block per
// 128-row bucket. (a) stage bucket entries in registers (8/thread),
// LDS-histogram rows; (b) scan -> per-row starts; (c) scatter entries
// row-sorted into LDS; (d) R5-style pull agg per node: 8 slots x 8 lanes,
// 16 edges in flight, score = s_row[v] + s_col[col] (L2-resident gather)
// + ea3 + ab -- no per-edge cross-lane ops.
__global__ __launch_bounds__(512) void k_sagg(
    const int2* __restrict__ entA, const int* __restrict__ cnt,
    const int* __restrict__ bbase, const __half* __restrict__ wh,
    const float* __restrict__ s_row, const float* __restrict__ s_col,
    const float* __restrict__ a_b, float* __restrict__ out, int n_nodes) {
  __shared__ int2 entl[ENTL];
  __shared__ int hist[RPB], sd[RPB], starts[RPB], curs[RPB], degs[RPB];
  const int b = blockIdx.x;
  const int row0 = b << 7;
  const int t = threadIdx.x;
  if (t < RPB) hist[t] = 0;
  __syncthreads();
  const int c = cnt[b];       // padded count (sentinels included)
  const int base = bbase[b];
  // --- stage + histogram ---
  int2 e[8];
#pragma unroll
  for (int k = 0; k < 8; ++k) {
    int i = t + k * 512;
    e[k] = (i < c) ? entA[base + i] : make_int2(-1, 0);
  }
#pragma unroll
  for (int k = 0; k < 8; ++k)
    if (e[k].x >= 0) atomicAdd(&hist[e[k].x >> 17], 1);
  for (int i = t + 4096; i < c; i += 512) {  // overflow guard (never runs)
    int2 p = entA[base + i];
    if (p.x >= 0) atomicAdd(&hist[p.x >> 17], 1);
  }
  __syncthreads();
  // --- scan hist[128] ---
  int hh = 0;
  if (t < RPB) { hh = hist[t]; sd[t] = hh; }
  __syncthreads();
  for (int off = 1; off < RPB; off <<= 1) {
    int x = (t >= off && t < RPB) ? sd[t - off] : 0;
    __syncthreads();
    if (t < RPB) sd[t] += x;
    __syncthreads();
  }
  if (t < RPB) {
    int excl = sd[t] - hh;
    starts[t] = excl;
    curs[t] = excl;
    degs[t] = hh;
  }
  __syncthreads();
  // --- scatter row-sorted into LDS ---
#pragma unroll
  for (int k = 0; k < 8; ++k)
    if (e[k].x >= 0) {
      int p = atomicAdd(&curs[e[k].x >> 17], 1);
      if (p < ENTL) entl[p] = e[k];
    }
  for (int i = t + 4096; i < c; i += 512) {  // overflow guard (never runs)
    int2 p2 = entA[base + i];
    if (p2.x >= 0) {
      int p = atomicAdd(&curs[p2.x >> 17], 1);
      if (p < ENTL) entl[p] = p2;
    }
  }
  __syncthreads();
  // --- aggregate: 8 waves x 16 nodes each ---
  const int wv = t >> 6;
  const int lane = t & 63;
  const int slot = lane >> 3, sub = lane & 7;
  const float ab = a_b[0];
  const uint4* whq = (const uint4*)wh;
  for (int j = 0; j < 16; ++j) {
    const int rl = wv * 16 + j;
    const int node = row0 + rl;
    if (node >= n_nodes) break;
    const int st = starts[rl];
    const int dg = degs[rl];
    const float sab = s_row[node] + ab;
    float acc[8] = {0.f, 0.f, 0.f, 0.f, 0.f, 0.f, 0.f, 0.f};
    float l = 0.f;
    for (int bas = 0; bas < dg; bas += 16) {
      const int i0 = bas + slot, i1 = bas + 8 + slot;
      const bool g0 = i0 < dg, g1 = i1 < dg;
      int2 p0 = g0 ? entl[st + i0] : make_int2(0, 0);
      int2 p1 = g1 ? entl[st + i1] : make_int2(0, 0);
      const int col0 = p0.x & 0x1FFFF, col1 = p1.x & 0x1FFFF;
      uint4 q0 = make_uint4(0, 0, 0, 0), q1 = make_uint4(0, 0, 0, 0);
      float sc0 = 0.f, sc1 = 0.f;
      if (g0) { q0 = whq[(size_t)col0 * 8 + sub]; sc0 = s_col[col0]; }
      if (g1) { q1 = whq[(size_t)col1 * 8 + sub]; sc1 = s_col[col1]; }
      if (g0) {
        float s = sab + sc0 + __int_as_float(p0.y);
        float ev = (s > 0.f) ? s : 0.01f * s;  // leaky_relu
        float a = __expf(ev);  // softmax shift-invariance: no segment max
        float2 f0 = __half22float2(*(__half2*)&q0.x);
        float2 f1 = __half22float2(*(__half2*)&q0.y);
        float2 f2 = __half22float2(*(__half2*)&q0.z);
        float2 f3 = __half22float2(*(__half2*)&q0.w);
        acc[0] = fmaf(a, f0.x, acc[0]); acc[1] = fmaf(a, f0.y, acc[1]);
        acc[2] = fmaf(a, f1.x, acc[2]); acc[3] = fmaf(a, f1.y, acc[3]);
        acc[4] = fmaf(a, f2.x, acc[4]); acc[5] = fmaf(a, f2.y, acc[5]);
        acc[6] = fmaf(a, f3.x, acc[6]); acc[7] = fmaf(a, f3.y, acc[7]);
        if (sub == 0) l += a;
      }
      if (g1) {
        float s = sab + sc1 + __int_as_float(p1.y);
        float ev = (s > 0.f) ? s : 0.01f * s;
        float a = __expf(ev);
        float2 f0 = __half22float2(*(__half2*)&q1.x);
        float2 f1 = __half22float2(*(__half2*)&q1.y);
        float2 f2 = __half22float2(*(__half2*)&q1.z);
        float2 f3 = __half22float2(*(__half2*)&q1.w);
        acc[0] = fmaf(a, f0.x, acc[0]); acc[1] = fmaf(a, f0.y, acc[1]);
        acc[2] = fmaf(a, f1.x, acc[2]); acc[3] = fmaf(a, f1.y, acc[3]);
        acc[4] = fmaf(a, f2.x, acc[4]); acc[5] = fmaf(a, f2.y, acc[5]);
        acc[6] = fmaf(a, f3.x, acc[6]); acc[7] = fmaf(a, f3.y, acc[7]);
        if (sub == 0) l += a;
      }
    }
#pragma unroll
    for (int d = 0; d < 8; ++d) {
      acc[d] += __shfl_xor(acc[d], 8, 64);
      acc[d] += __shfl_xor(acc[d], 16, 64);
      acc[d] += __shfl_xor(acc[d], 32, 64);
    }
    l += __shfl_xor(l, 8, 64);
    l += __shfl_xor(l, 16, 64);
    l += __shfl_xor(l, 32, 64);
    float lt = __shfl(l, 0, 64);
    if (slot == 0) {
      float inv = 1.0f / (lt + 1e-8f);
      float4 o0 = make_float4(acc[0] * inv, acc[1] * inv, acc[2] * inv,
                              acc[3] * inv);
      float4 o1 = make_float4(acc[4] * inv, acc[5] * inv, acc[6] * inv,
                              acc[7] * inv);
      float4* orow = (float4*)out + (size_t)node * 16 + sub * 2;
      orow[0] = o0;
      orow[1] = o1;
    }
  }
}

extern "C" void kernel_launch(void* const* d_in, const int* in_sizes, int n_in,
                              void* d_out, int out_size, void* d_ws, size_t ws_size,
                              hipStream_t stream) {
  const float* h         = (const float*)d_in[0];
  const int*   ei        = (const int*)d_in[1];
  const float* edge_attr = (const float*)d_in[2];
  const float* w_w       = (const float*)d_in[3];
  const float* w_b       = (const float*)d_in[4];
  const float* a_w       = (const float*)d_in[5];
  const float* a_b       = (const float*)d_in[6];
  const int n_nodes = in_sizes[0] / IN_DIM;
  const int nedges  = in_sizes[1] / 2;
  const int nb   = (n_nodes + RPB - 1) / RPB;   // 782
  const int nebl = (nedges + EPB - 1) / EPB;    // 391

  // entA capacity with line padding: nedges + nebl*nb*8 + nb*16
  const size_t entcap = (size_t)nedges + (size_t)nebl * nb * 8 + (size_t)nb * 16;

  // Workspace (~49 MB):
  __half* wh       = (__half*)d_ws;                           // n*64 fp16
  int2*  entA      = (int2*)(wh + (size_t)n_nodes * OUT_DIM); // entcap
  int*   cnt       = (int*)(entA + entcap);                   // MAXB
  int*   bbase     = cnt + MAXB;                              // MAXB
  float* s_row     = (float*)(bbase + MAXB);                  // n
  float* s_col     = s_row + n_nodes;                         // n
  int*   blockhist = (int*)(s_col + n_nodes);                 // nebl*MAXB
  int*   boff      = blockhist + (size_t)nebl * MAXB;         // nebl*MAXB

  k_wh<<<640, 256, 0, stream>>>(h, w_w, w_b, a_w, wh, s_row, s_col, n_nodes);
  k_pre<<<nebl, 512, 0, stream>>>(ei, blockhist, nedges);
  k_scanA<<<nb, 512, 0, stream>>>(blockhist, boff, cnt, nebl);
  k_scanB<<<1, 512, 0, stream>>>(cnt, bbase, nb);
  k_fill<<<nebl, 512, 0, stream>>>(ei, edge_attr, a_w, boff, bbase, entA,
                                   nedges, nb);
  k_sagg<<<nb, 512, 0, stream>>>(entA, cnt, bbase, wh, s_row, s_col, a_b,
                                 (float*)d_out, n_nodes);
}

// Round 8
// 234.914 us; speedup vs baseline: 3.7824x; 1.0873x over previous
//
#include <hip/hip_runtime.h>
#include <hip/hip_fp16.h>

#define IN_DIM 128
#define OUT_DIM 64
#define RPB 128          // rows per bucket (in-LDS sort+agg)
#define MAXB 800         // max buckets  (n_nodes <= 102400)
#define EPB 4096         // edges per block in k_fill (512 thr x 8)
#define ENTL 2304        // LDS entry cap per bucket (mean 2048 + >5 sigma)
#define CAP 3584         // per-bucket entA region capacity (mean 3180 + 6 sigma)

typedef __attribute__((ext_vector_type(8))) _Float16 half8;
typedef __attribute__((ext_vector_type(4))) float f32x4;

// Phase 1 (MFMA): wh = h @ w_w + w_b (stored fp16); s_row = wh@a1; s_col = wh@a2.
// Also zeroes the per-bucket global allocation cursors (gcur).
__global__ __launch_bounds__(256) void k_wh(
    const float* __restrict__ h, const float* __restrict__ w_w,
    const float* __restrict__ w_b, const float* __restrict__ a_w,
    __half* __restrict__ wh, float* __restrict__ s_row,
    float* __restrict__ s_col, int* __restrict__ gcur, int n_nodes) {
  {
    int tid = blockIdx.x * 256 + threadIdx.x;
    if (tid < MAXB) gcur[tid] = 0;
  }
  __shared__ _Float16 wf[4 * 4 * 64 * 8];
  for (int idx = threadIdx.x; idx < IN_DIM * OUT_DIM; idx += 256) {
    int k = idx >> 6, c = idx & 63;            // w_w[k][c], coalesced read
    int mt = c >> 4;
    int kt = k >> 5;
    int l = (((k >> 3) & 3) << 4) | (c & 15);  // lane that owns this (k,c)
    int j = k & 7;
    wf[(((mt << 2) | kt) << 9) | (l << 3) | j] = (_Float16)w_w[idx];
  }
  __syncthreads();

  const int lane = threadIdx.x & 63;
  const int wv = threadIdx.x >> 6;

  half8 A[4][4];
#pragma unroll
  for (int mt = 0; mt < 4; ++mt)
#pragma unroll
    for (int kt = 0; kt < 4; ++kt)
      A[mt][kt] =
          *(const half8*)&wf[(((mt << 2) | kt) << 9) | (lane << 3)];

  const int cbase = (lane >> 4) << 2;
  f32x4 bq[4], a1q[4], a2q[4];
#pragma unroll
  for (int mt = 0; mt < 4; ++mt) {
    bq[mt] = *(const f32x4*)&w_b[mt * 16 + cbase];
    a1q[mt] = *(const f32x4*)&a_w[mt * 16 + cbase];
    a2q[mt] = *(const f32x4*)&a_w[OUT_DIM + mt * 16 + cbase];
  }

  const int ntiles = (n_nodes + 15) >> 4;
  const int tstride = gridDim.x << 2;
  for (int t = blockIdx.x * 4 + wv; t < ntiles; t += tstride) {
    const int n0 = t << 4;
    const int node = n0 + (lane & 15);
    const int nodec = node < n_nodes ? node : n_nodes - 1;
    const float4* hv =
        (const float4*)(h + (size_t)nodec * IN_DIM + ((lane >> 4) << 3));
    float4 p[8];
#pragma unroll
    for (int kt = 0; kt < 4; ++kt) {
      p[2 * kt] = hv[kt * 8];
      p[2 * kt + 1] = hv[kt * 8 + 1];
    }
    f32x4 C[4];
#pragma unroll
    for (int mt = 0; mt < 4; ++mt) C[mt] = (f32x4){0.f, 0.f, 0.f, 0.f};
#pragma unroll
    for (int kt = 0; kt < 4; ++kt) {
      const float4 u = p[2 * kt], v = p[2 * kt + 1];
      half8 B;
      B[0] = (_Float16)u.x; B[1] = (_Float16)u.y;
      B[2] = (_Float16)u.z; B[3] = (_Float16)u.w;
      B[4] = (_Float16)v.x; B[5] = (_Float16)v.y;
      B[6] = (_Float16)v.z; B[7] = (_Float16)v.w;
#pragma unroll
      for (int mt = 0; mt < 4; ++mt)
        C[mt] = __builtin_amdgcn_mfma_f32_16x16x32_f16(A[mt][kt], B, C[mt],
                                                       0, 0, 0);
    }
    float sr = 0.f, sc = 0.f;
    uint2 q[4];
#pragma unroll
    for (int mt = 0; mt < 4; ++mt) {
      f32x4 d = C[mt] + bq[mt];
      sr += d[0] * a1q[mt][0] + d[1] * a1q[mt][1] + d[2] * a1q[mt][2] +
            d[3] * a1q[mt][3];
      sc += d[0] * a2q[mt][0] + d[1] * a2q[mt][1] + d[2] * a2q[mt][2] +
            d[3] * a2q[mt][3];
      __half2 lo = __floats2half2_rn(d[0], d[1]);
      __half2 hi = __floats2half2_rn(d[2], d[3]);
      q[mt].x = *(unsigned int*)&lo;
      q[mt].y = *(unsigned int*)&hi;
    }
    if (node < n_nodes) {
      uint2* wrow = (uint2*)(wh + (size_t)node * OUT_DIM + cbase);
      wrow[0] = q[0];
      wrow[4] = q[1];
      wrow[8] = q[2];
      wrow[12] = q[3];
    }
    sr += __shfl_xor(sr, 16, 64);
    sr += __shfl_xor(sr, 32, 64);
    sc += __shfl_xor(sc, 16, 64);
    sc += __shfl_xor(sc, 32, 64);
    if (lane < 16 && node < n_nodes) {
      s_row[node] = sr;
      s_col[node] = sc;
    }
  }
}

// Phase 2 (fused count+alloc+fill): per block, (a) LDS-histogram its 4096
// edges per bucket (rows/cols/ea3 staged in registers), (b) grab one
// 8-entry-aligned chunk per touched bucket from the bucket's region
// (base b*CAP) via a single global atomicAdd, (c) scatter its run into the
// exclusive chunk, (d) sentinel-pad its own chunk tail. Every 64B line has
// exactly one writing block -> no cross-XCD partial-line amplification.
// Replaces k_pre + k_scanA + k_scanB + old k_fill.
__global__ __launch_bounds__(512) void k_fill(
    const int* __restrict__ ei, const float* __restrict__ edge_attr,
    const float* __restrict__ a_w, int* __restrict__ gcur,
    int2* __restrict__ entA, int nedges, int nb) {
  __shared__ int hist[MAXB];   // this block's per-bucket count
  __shared__ int cbase[MAXB];  // this block's chunk base (absolute)
  __shared__ int curs[MAXB];   // scatter cursor
  for (int b = threadIdx.x; b < MAXB; b += 512) hist[b] = 0;
  const float aw0 = a_w[128], aw1 = a_w[129], aw2 = a_w[130], aw3 = a_w[131];
  const float aw4 = a_w[132], aw5 = a_w[133], aw6 = a_w[134], aw7 = a_w[135];
  __syncthreads();
  const int e0 = blockIdx.x * EPB;
  int row[8], col[8];
  float s[8];
  // pass 1: stream loads + ea3 + histogram
#pragma unroll
  for (int k = 0; k < 8; ++k) {
    int e = e0 + k * 512 + threadIdx.x;
    if (e < nedges) {
      row[k] = ei[e];
      col[k] = ei[nedges + e];
    } else {
      row[k] = -1;
      col[k] = 0;
    }
  }
#pragma unroll
  for (int k = 0; k < 8; ++k) {
    int e = e0 + k * 512 + threadIdx.x;
    if (row[k] >= 0) {
      const float4* ea = (const float4*)(edge_attr + (size_t)e * 8);
      float4 u = ea[0], v = ea[1];
      float t = u.x * aw0 + u.y * aw1 + u.z * aw2 + u.w * aw3;
      t += v.x * aw4 + v.y * aw5 + v.z * aw6 + v.w * aw7;
      s[k] = t;
    } else {
      s[k] = 0.f;
    }
  }
#pragma unroll
  for (int k = 0; k < 8; ++k)
    if (row[k] >= 0) atomicAdd(&hist[row[k] >> 7], 1);
  __syncthreads();
  // pass 2: chunk allocation (one aligned chunk per touched bucket)
  for (int b = threadIdx.x; b < nb; b += 512) {
    int c = hist[b];
    int cb = 0;
    if (c > 0) cb = b * CAP + atomicAdd(&gcur[b], (c + 7) & ~7);
    cbase[b] = cb;
    curs[b] = cb;
  }
  __syncthreads();
  // pass 3: scatter into exclusive chunk
#pragma unroll
  for (int k = 0; k < 8; ++k) {
    if (row[k] >= 0) {
      int bb = row[k] >> 7;
      int pos = atomicAdd(&curs[bb], 1);
      entA[pos] = make_int2(((row[k] & 127) << 17) | col[k],
                            __float_as_int(s[k]));
    }
  }
  __syncthreads();
  // pass 4: sentinel-pad this block's chunk tails (same lines we own)
  for (int b = threadIdx.x; b < nb; b += 512) {
    int c = hist[b];
    if (c > 0) {
      int st = cbase[b] + c, end = cbase[b] + ((c + 7) & ~7);
      for (int k = st; k < end; ++k) entA[k] = make_int2(-1, 0);
    }
  }
}

// Phase 3 (fused sort+agg): one block per 128-row bucket. Stage bucket
// entries in registers, LDS-histogram rows, scan -> per-row starts,
// scatter row-sorted into LDS, then pull-agg per node (8 slots x 8 lanes,
// 16 edges in flight). Score = s_row[v] + s_col[col] + ea3 + ab.
__global__ __launch_bounds__(512) void k_sagg(
    const int2* __restrict__ entA, const int* __restrict__ gcur,
    const __half* __restrict__ wh,
    const float* __restrict__ s_row, const float* __restrict__ s_col,
    const float* __restrict__ a_b, float* __restrict__ out, int n_nodes) {
  __shared__ int2 entl[ENTL];
  __shared__ int hist[RPB], sd[RPB], starts[RPB], curs[RPB], degs[RPB];
  const int b = blockIdx.x;
  const int row0 = b << 7;
  const int t = threadIdx.x;
  if (t < RPB) hist[t] = 0;
  __syncthreads();
  const int c = gcur[b];       // padded count (sentinels included)
  const int base = b * CAP;
  // --- stage + histogram ---
  int2 e[8];
#pragma unroll
  for (int k = 0; k < 8; ++k) {
    int i = t + k * 512;
    e[k] = (i < c) ? entA[base + i] : make_int2(-1, 0);
  }
#pragma unroll
  for (int k = 0; k < 8; ++k)
    if (e[k].x >= 0) atomicAdd(&hist[e[k].x >> 17], 1);
  for (int i = t + 4096; i < c; i += 512) {  // overflow guard (never runs)
    int2 p = entA[base + i];
    if (p.x >= 0) atomicAdd(&hist[p.x >> 17], 1);
  }
  __syncthreads();
  // --- scan hist[128] ---
  int hh = 0;
  if (t < RPB) { hh = hist[t]; sd[t] = hh; }
  __syncthreads();
  for (int off = 1; off < RPB; off <<= 1) {
    int x = (t >= off && t < RPB) ? sd[t - off] : 0;
    __syncthreads();
    if (t < RPB) sd[t] += x;
    __syncthreads();
  }
  if (t < RPB) {
    int excl = sd[t] - hh;
    starts[t] = excl;
    curs[t] = excl;
    degs[t] = hh;
  }
  __syncthreads();
  // --- scatter row-sorted into LDS ---
#pragma unroll
  for (int k = 0; k < 8; ++k)
    if (e[k].x >= 0) {
      int p = atomicAdd(&curs[e[k].x >> 17], 1);
      if (p < ENTL) entl[p] = e[k];
    }
  for (int i = t + 4096; i < c; i += 512) {  // overflow guard (never runs)
    int2 p2 = entA[base + i];
    if (p2.x >= 0) {
      int p = atomicAdd(&curs[p2.x >> 17], 1);
      if (p < ENTL) entl[p] = p2;
    }
  }
  __syncthreads();
  // --- aggregate: 8 waves x 16 nodes each ---
  const int wv = t >> 6;
  const int lane = t & 63;
  const int slot = lane >> 3, sub = lane & 7;
  const float ab = a_b[0];
  const uint4* whq = (const uint4*)wh;
  for (int j = 0; j < 16; ++j) {
    const int rl = wv * 16 + j;
    const int node = row0 + rl;
    if (node >= n_nodes) break;
    const int st = starts[rl];
    const int dg = degs[rl];
    const float sab = s_row[node] + ab;
    float acc[8] = {0.f, 0.f, 0.f, 0.f, 0.f, 0.f, 0.f, 0.f};
    float l = 0.f;
    for (int bas = 0; bas < dg; bas += 16) {
      const int i0 = bas + slot, i1 = bas + 8 + slot;
      const bool g0 = i0 < dg, g1 = i1 < dg;
      int2 p0 = g0 ? entl[st + i0] : make_int2(0, 0);
      int2 p1 = g1 ? entl[st + i1] : make_int2(0, 0);
      const int col0 = p0.x & 0x1FFFF, col1 = p1.x & 0x1FFFF;
      uint4 q0 = make_uint4(0, 0, 0, 0), q1 = make_uint4(0, 0, 0, 0);
      float sc0 = 0.f, sc1 = 0.f;
      if (g0) { q0 = whq[(size_t)col0 * 8 + sub]; sc0 = s_col[col0]; }
      if (g1) { q1 = whq[(size_t)col1 * 8 + sub]; sc1 = s_col[col1]; }
      if (g0) {
        float s = sab + sc0 + __int_as_float(p0.y);
        float ev = (s > 0.f) ? s : 0.01f * s;  // leaky_relu
        float a = __expf(ev);  // softmax shift-invariance: no segment max
        float2 f0 = __half22float2(*(__half2*)&q0.x);
        float2 f1 = __half22float2(*(__half2*)&q0.y);
        float2 f2 = __half22float2(*(__half2*)&q0.z);
        float2 f3 = __half22float2(*(__half2*)&q0.w);
        acc[0] = fmaf(a, f0.x, acc[0]); acc[1] = fmaf(a, f0.y, acc[1]);
        acc[2] = fmaf(a, f1.x, acc[2]); acc[3] = fmaf(a, f1.y, acc[3]);
        acc[4] = fmaf(a, f2.x, acc[4]); acc[5] = fmaf(a, f2.y, acc[5]);
        acc[6] = fmaf(a, f3.x, acc[6]); acc[7] = fmaf(a, f3.y, acc[7]);
        if (sub == 0) l += a;
      }
      if (g1) {
        float s = sab + sc1 + __int_as_float(p1.y);
        float ev = (s > 0.f) ? s : 0.01f * s;
        float a = __expf(ev);
        float2 f0 = __half22float2(*(__half2*)&q1.x);
        float2 f1 = __half22float2(*(__half2*)&q1.y);
        float2 f2 = __half22float2(*(__half2*)&q1.z);
        float2 f3 = __half22float2(*(__half2*)&q1.w);
        acc[0] = fmaf(a, f0.x, acc[0]); acc[1] = fmaf(a, f0.y, acc[1]);
        acc[2] = fmaf(a, f1.x, acc[2]); acc[3] = fmaf(a, f1.y, acc[3]);
        acc[4] = fmaf(a, f2.x, acc[4]); acc[5] = fmaf(a, f2.y, acc[5]);
        acc[6] = fmaf(a, f3.x, acc[6]); acc[7] = fmaf(a, f3.y, acc[7]);
        if (sub == 0) l += a;
      }
    }
#pragma unroll
    for (int d = 0; d < 8; ++d) {
      acc[d] += __shfl_xor(acc[d], 8, 64);
      acc[d] += __shfl_xor(acc[d], 16, 64);
      acc[d] += __shfl_xor(acc[d], 32, 64);
    }
    l += __shfl_xor(l, 8, 64);
    l += __shfl_xor(l, 16, 64);
    l += __shfl_xor(l, 32, 64);
    float lt = __shfl(l, 0, 64);
    if (slot == 0) {
      float inv = 1.0f / (lt + 1e-8f);
      float4 o0 = make_float4(acc[0] * inv, acc[1] * inv, acc[2] * inv,
                              acc[3] * inv);
      float4 o1 = make_float4(acc[4] * inv, acc[5] * inv, acc[6] * inv,
                              acc[7] * inv);
      float4* orow = (float4*)out + (size_t)node * 16 + sub * 2;
      orow[0] = o0;
      orow[1] = o1;
    }
  }
}

extern "C" void kernel_launch(void* const* d_in, const int* in_sizes, int n_in,
                              void* d_out, int out_size, void* d_ws, size_t ws_size,
                              hipStream_t stream) {
  const float* h         = (const float*)d_in[0];
  const int*   ei        = (const int*)d_in[1];
  const float* edge_attr = (const float*)d_in[2];
  const float* w_w       = (const float*)d_in[3];
  const float* w_b       = (const float*)d_in[4];
  const float* a_w       = (const float*)d_in[5];
  const float* a_b       = (const float*)d_in[6];
  const int n_nodes = in_sizes[0] / IN_DIM;
  const int nedges  = in_sizes[1] / 2;
  const int nb   = (n_nodes + RPB - 1) / RPB;   // 782
  const int nebl = (nedges + EPB - 1) / EPB;    // 391

  // Workspace (~36 MB): wh | entA (nb*CAP) | gcur | s_row | s_col
  __half* wh       = (__half*)d_ws;                           // n*64 fp16
  int2*  entA      = (int2*)(wh + (size_t)n_nodes * OUT_DIM); // nb*CAP
  int*   gcur      = (int*)(entA + (size_t)nb * CAP);         // MAXB
  float* s_row     = (float*)(gcur + MAXB);                   // n
  float* s_col     = s_row + n_nodes;                         // n

  k_wh<<<640, 256, 0, stream>>>(h, w_w, w_b, a_w, wh, s_row, s_col, gcur,
                                n_nodes);
  k_fill<<<nebl, 512, 0, stream>>>(ei, edge_attr, a_w, gcur, entA,
                                   nedges, nb);
  k_sagg<<<nb, 512, 0, stream>>>(entA, gcur, wh, s_row, s_col, a_b,
                                 (float*)d_out, n_nodes);
}

// Round 9
// 223.843 us; speedup vs baseline: 3.9695x; 1.0495x over previous
//
#include <hip/hip_runtime.h>
#include <hip/hip_fp16.h>

#define IN_DIM 128
#define OUT_DIM 64
#define RPB 128          // rows per bucket (in-LDS sort+agg)
#define MAXB 800         // max buckets  (n_nodes <= 102400)
#define EPB 4096         // edges per block in fill part (512 thr x 8)
#define ENTL 2304        // LDS entry cap per bucket (mean 2048 + >5 sigma)
#define CAP 3584         // per-bucket entA region capacity (mean 3180 + 6 sigma)
#define NWH 320          // wh-part blocks (8 waves each = 2560 wave-slots)

typedef __attribute__((ext_vector_type(8))) _Float16 half8;
typedef __attribute__((ext_vector_type(4))) float f32x4;

// Tiny prologue: zero the per-bucket allocation cursors. Must be a separate
// launch (fill blocks may not assume any cross-block dispatch ordering).
__global__ __launch_bounds__(256) void k_zero(int* __restrict__ gcur) {
  for (int i = threadIdx.x; i < MAXB; i += 256) gcur[i] = 0;
}

// Fat kernel: blocks [0,nfill) = fill body, blocks [nfill,nfill+NWH) = wh
// body. The two are data-independent (fill: ei/edge_attr -> entA; wh:
// h/weights -> wh/s_row/s_col) and stress different pipes, so they
// co-schedule instead of serializing as two launches.
__global__ __launch_bounds__(512) void k_whfill(
    const float* __restrict__ h, const float* __restrict__ w_w,
    const float* __restrict__ w_b, const float* __restrict__ a_w,
    const int* __restrict__ ei, const float* __restrict__ edge_attr,
    __half* __restrict__ wh, float* __restrict__ s_row,
    float* __restrict__ s_col, int* __restrict__ gcur,
    int2* __restrict__ entA, int n_nodes, int nedges, int nb, int nfill) {
  if ((int)blockIdx.x < nfill) {
    // ---------------- fill body (R8 k_fill, unchanged logic) ----------------
    __shared__ int hist[MAXB];   // this block's per-bucket count
    __shared__ int cbase[MAXB];  // this block's chunk base (absolute)
    __shared__ int curs[MAXB];   // scatter cursor
    for (int b = threadIdx.x; b < MAXB; b += 512) hist[b] = 0;
    const float aw0 = a_w[128], aw1 = a_w[129], aw2 = a_w[130], aw3 = a_w[131];
    const float aw4 = a_w[132], aw5 = a_w[133], aw6 = a_w[134], aw7 = a_w[135];
    __syncthreads();
    const int e0 = blockIdx.x * EPB;
    int row[8], col[8];
    float s[8];
#pragma unroll
    for (int k = 0; k < 8; ++k) {
      int e = e0 + k * 512 + threadIdx.x;
      if (e < nedges) {
        row[k] = ei[e];
        col[k] = ei[nedges + e];
      } else {
        row[k] = -1;
        col[k] = 0;
      }
    }
#pragma unroll
    for (int k = 0; k < 8; ++k) {
      int e = e0 + k * 512 + threadIdx.x;
      if (row[k] >= 0) {
        const float4* ea = (const float4*)(edge_attr + (size_t)e * 8);
        float4 u = ea[0], v = ea[1];
        float t = u.x * aw0 + u.y * aw1 + u.z * aw2 + u.w * aw3;
        t += v.x * aw4 + v.y * aw5 + v.z * aw6 + v.w * aw7;
        s[k] = t;
      } else {
        s[k] = 0.f;
      }
    }
#pragma unroll
    for (int k = 0; k < 8; ++k)
      if (row[k] >= 0) atomicAdd(&hist[row[k] >> 7], 1);
    __syncthreads();
    for (int b = threadIdx.x; b < nb; b += 512) {
      int c = hist[b];
      int cb = 0;
      if (c > 0) cb = b * CAP + atomicAdd(&gcur[b], (c + 7) & ~7);
      cbase[b] = cb;
      curs[b] = cb;
    }
    __syncthreads();
#pragma unroll
    for (int k = 0; k < 8; ++k) {
      if (row[k] >= 0) {
        int bb = row[k] >> 7;
        int pos = atomicAdd(&curs[bb], 1);
        entA[pos] = make_int2(((row[k] & 127) << 17) | col[k],
                              __float_as_int(s[k]));
      }
    }
    __syncthreads();
    for (int b = threadIdx.x; b < nb; b += 512) {
      int c = hist[b];
      if (c > 0) {
        int st = cbase[b] + c, end = cbase[b] + ((c + 7) & ~7);
        for (int k = st; k < end; ++k) entA[k] = make_int2(-1, 0);
      }
    }
  } else {
    // ---------------- wh body (MFMA, 8 waves per block) ----------------
    __shared__ _Float16 wf[4 * 4 * 64 * 8];
    for (int idx = threadIdx.x; idx < IN_DIM * OUT_DIM; idx += 512) {
      int k = idx >> 6, c = idx & 63;            // w_w[k][c], coalesced read
      int mt = c >> 4;
      int kt = k >> 5;
      int l = (((k >> 3) & 3) << 4) | (c & 15);  // lane owning this (k,c)
      int j = k & 7;
      wf[(((mt << 2) | kt) << 9) | (l << 3) | j] = (_Float16)w_w[idx];
    }
    __syncthreads();

    const int lane = threadIdx.x & 63;
    const int wv = threadIdx.x >> 6;            // 0..7

    half8 A[4][4];
#pragma unroll
    for (int mt = 0; mt < 4; ++mt)
#pragma unroll
      for (int kt = 0; kt < 4; ++kt)
        A[mt][kt] =
            *(const half8*)&wf[(((mt << 2) | kt) << 9) | (lane << 3)];

    const int cbase2 = (lane >> 4) << 2;
    f32x4 bq[4], a1q[4], a2q[4];
#pragma unroll
    for (int mt = 0; mt < 4; ++mt) {
      bq[mt] = *(const f32x4*)&w_b[mt * 16 + cbase2];
      a1q[mt] = *(const f32x4*)&a_w[mt * 16 + cbase2];
      a2q[mt] = *(const f32x4*)&a_w[OUT_DIM + mt * 16 + cbase2];
    }

    const int wb = blockIdx.x - nfill;
    const int ntiles = (n_nodes + 15) >> 4;
    const int tstride = NWH * 8;
    for (int t = wb * 8 + wv; t < ntiles; t += tstride) {
      const int n0 = t << 4;
      const int node = n0 + (lane & 15);
      const int nodec = node < n_nodes ? node : n_nodes - 1;
      const float4* hv =
          (const float4*)(h + (size_t)nodec * IN_DIM + ((lane >> 4) << 3));
      float4 p[8];
#pragma unroll
      for (int kt = 0; kt < 4; ++kt) {
        p[2 * kt] = hv[kt * 8];
        p[2 * kt + 1] = hv[kt * 8 + 1];
      }
      f32x4 C[4];
#pragma unroll
      for (int mt = 0; mt < 4; ++mt) C[mt] = (f32x4){0.f, 0.f, 0.f, 0.f};
#pragma unroll
      for (int kt = 0; kt < 4; ++kt) {
        const float4 u = p[2 * kt], v = p[2 * kt + 1];
        half8 B;
        B[0] = (_Float16)u.x; B[1] = (_Float16)u.y;
        B[2] = (_Float16)u.z; B[3] = (_Float16)u.w;
        B[4] = (_Float16)v.x; B[5] = (_Float16)v.y;
        B[6] = (_Float16)v.z; B[7] = (_Float16)v.w;
#pragma unroll
        for (int mt = 0; mt < 4; ++mt)
          C[mt] = __builtin_amdgcn_mfma_f32_16x16x32_f16(A[mt][kt], B, C[mt],
                                                         0, 0, 0);
      }
      float sr = 0.f, sc = 0.f;
      uint2 q[4];
#pragma unroll
      for (int mt = 0; mt < 4; ++mt) {
        f32x4 d = C[mt] + bq[mt];
        sr += d[0] * a1q[mt][0] + d[1] * a1q[mt][1] + d[2] * a1q[mt][2] +
              d[3] * a1q[mt][3];
        sc += d[0] * a2q[mt][0] + d[1] * a2q[mt][1] + d[2] * a2q[mt][2] +
              d[3] * a2q[mt][3];
        __half2 lo = __floats2half2_rn(d[0], d[1]);
        __half2 hi = __floats2half2_rn(d[2], d[3]);
        q[mt].x = *(unsigned int*)&lo;
        q[mt].y = *(unsigned int*)&hi;
      }
      if (node < n_nodes) {
        uint2* wrow = (uint2*)(wh + (size_t)node * OUT_DIM + cbase2);
        wrow[0] = q[0];
        wrow[4] = q[1];
        wrow[8] = q[2];
        wrow[12] = q[3];
      }
      sr += __shfl_xor(sr, 16, 64);
      sr += __shfl_xor(sr, 32, 64);
      sc += __shfl_xor(sc, 16, 64);
      sc += __shfl_xor(sc, 32, 64);
      if (lane < 16 && node < n_nodes) {
        s_row[node] = sr;
        s_col[node] = sc;
      }
    }
  }
}

// Phase 3 (fused sort+agg): one block per 128-row bucket. Stage bucket
// entries in registers, LDS-histogram rows, scan -> per-row starts,
// scatter row-sorted into LDS, then pull-agg per node (8 slots x 8 lanes,
// 16 edges in flight). Score = s_row[v] + s_col[col] + ea3 + ab.
__global__ __launch_bounds__(512) void k_sagg(
    const int2* __restrict__ entA, const int* __restrict__ gcur,
    const __half* __restrict__ wh,
    const float* __restrict__ s_row, const float* __restrict__ s_col,
    const float* __restrict__ a_b, float* __restrict__ out, int n_nodes) {
  __shared__ int2 entl[ENTL];
  __shared__ int hist[RPB], sd[RPB], starts[RPB], curs[RPB], degs[RPB];
  const int b = blockIdx.x;
  const int row0 = b << 7;
  const int t = threadIdx.x;
  if (t < RPB) hist[t] = 0;
  __syncthreads();
  const int c = gcur[b];       // padded count (sentinels included)
  const int base = b * CAP;
  // --- stage + histogram ---
  int2 e[8];
#pragma unroll
  for (int k = 0; k < 8; ++k) {
    int i = t + k * 512;
    e[k] = (i < c) ? entA[base + i] : make_int2(-1, 0);
  }
#pragma unroll
  for (int k = 0; k < 8; ++k)
    if (e[k].x >= 0) atomicAdd(&hist[e[k].x >> 17], 1);
  for (int i = t + 4096; i < c; i += 512) {  // overflow guard (never runs)
    int2 p = entA[base + i];
    if (p.x >= 0) atomicAdd(&hist[p.x >> 17], 1);
  }
  __syncthreads();
  // --- scan hist[128] ---
  int hh = 0;
  if (t < RPB) { hh = hist[t]; sd[t] = hh; }
  __syncthreads();
  for (int off = 1; off < RPB; off <<= 1) {
    int x = (t >= off && t < RPB) ? sd[t - off] : 0;
    __syncthreads();
    if (t < RPB) sd[t] += x;
    __syncthreads();
  }
  if (t < RPB) {
    int excl = sd[t] - hh;
    starts[t] = excl;
    curs[t] = excl;
    degs[t] = hh;
  }
  __syncthreads();
  // --- scatter row-sorted into LDS ---
#pragma unroll
  for (int k = 0; k < 8; ++k)
    if (e[k].x >= 0) {
      int p = atomicAdd(&curs[e[k].x >> 17], 1);
      if (p < ENTL) entl[p] = e[k];
    }
  for (int i = t + 4096; i < c; i += 512) {  // overflow guard (never runs)
    int2 p2 = entA[base + i];
    if (p2.x >= 0) {
      int p = atomicAdd(&curs[p2.x >> 17], 1);
      if (p < ENTL) entl[p] = p2;
    }
  }
  __syncthreads();
  // --- aggregate: 8 waves x 16 nodes each ---
  const int wv = t >> 6;
  const int lane = t & 63;
  const int slot = lane >> 3, sub = lane & 7;
  const float ab = a_b[0];
  const uint4* whq = (const uint4*)wh;
  for (int j = 0; j < 16; ++j) {
    const int rl = wv * 16 + j;
    const int node = row0 + rl;
    if (node >= n_nodes) break;
    const int st = starts[rl];
    const int dg = degs[rl];
    const float sab = s_row[node] + ab;
    float acc[8] = {0.f, 0.f, 0.f, 0.f, 0.f, 0.f, 0.f, 0.f};
    float l = 0.f;
    for (int bas = 0; bas < dg; bas += 16) {
      const int i0 = bas + slot, i1 = bas + 8 + slot;
      const bool g0 = i0 < dg, g1 = i1 < dg;
      int2 p0 = g0 ? entl[st + i0] : make_int2(0, 0);
      int2 p1 = g1 ? entl[st + i1] : make_int2(0, 0);
      const int col0 = p0.x & 0x1FFFF, col1 = p1.x & 0x1FFFF;
      uint4 q0 = make_uint4(0, 0, 0, 0), q1 = make_uint4(0, 0, 0, 0);
      float sc0 = 0.f, sc1 = 0.f;
      if (g0) { q0 = whq[(size_t)col0 * 8 + sub]; sc0 = s_col[col0]; }
      if (g1) { q1 = whq[(size_t)col1 * 8 + sub]; sc1 = s_col[col1]; }
      if (g0) {
        float s = sab + sc0 + __int_as_float(p0.y);
        float ev = (s > 0.f) ? s : 0.01f * s;  // leaky_relu
        float a = __expf(ev);  // softmax shift-invariance: no segment max
        float2 f0 = __half22float2(*(__half2*)&q0.x);
        float2 f1 = __half22float2(*(__half2*)&q0.y);
        float2 f2 = __half22float2(*(__half2*)&q0.z);
        float2 f3 = __half22float2(*(__half2*)&q0.w);
        acc[0] = fmaf(a, f0.x, acc[0]); acc[1] = fmaf(a, f0.y, acc[1]);
        acc[2] = fmaf(a, f1.x, acc[2]); acc[3] = fmaf(a, f1.y, acc[3]);
        acc[4] = fmaf(a, f2.x, acc[4]); acc[5] = fmaf(a, f2.y, acc[5]);
        acc[6] = fmaf(a, f3.x, acc[6]); acc[7] = fmaf(a, f3.y, acc[7]);
        if (sub == 0) l += a;
      }
      if (g1) {
        float s = sab + sc1 + __int_as_float(p1.y);
        float ev = (s > 0.f) ? s : 0.01f * s;
        float a = __expf(ev);
        float2 f0 = __half22float2(*(__half2*)&q1.x);
        float2 f1 = __half22float2(*(__half2*)&q1.y);
        float2 f2 = __half22float2(*(__half2*)&q1.z);
        float2 f3 = __half22float2(*(__half2*)&q1.w);
        acc[0] = fmaf(a, f0.x, acc[0]); acc[1] = fmaf(a, f0.y, acc[1]);
        acc[2] = fmaf(a, f1.x, acc[2]); acc[3] = fmaf(a, f1.y, acc[3]);
        acc[4] = fmaf(a, f2.x, acc[4]); acc[5] = fmaf(a, f2.y, acc[5]);
        acc[6] = fmaf(a, f3.x, acc[6]); acc[7] = fmaf(a, f3.y, acc[7]);
        if (sub == 0) l += a;
      }
    }
#pragma unroll
    for (int d = 0; d < 8; ++d) {
      acc[d] += __shfl_xor(acc[d], 8, 64);
      acc[d] += __shfl_xor(acc[d], 16, 64);
      acc[d] += __shfl_xor(acc[d], 32, 64);
    }
    l += __shfl_xor(l, 8, 64);
    l += __shfl_xor(l, 16, 64);
    l += __shfl_xor(l, 32, 64);
    float lt = __shfl(l, 0, 64);
    if (slot == 0) {
      float inv = 1.0f / (lt + 1e-8f);
      float4 o0 = make_float4(acc[0] * inv, acc[1] * inv, acc[2] * inv,
                              acc[3] * inv);
      float4 o1 = make_float4(acc[4] * inv, acc[5] * inv, acc[6] * inv,
                              acc[7] * inv);
      float4* orow = (float4*)out + (size_t)node * 16 + sub * 2;
      orow[0] = o0;
      orow[1] = o1;
    }
  }
}

extern "C" void kernel_launch(void* const* d_in, const int* in_sizes, int n_in,
                              void* d_out, int out_size, void* d_ws, size_t ws_size,
                              hipStream_t stream) {
  const float* h         = (const float*)d_in[0];
  const int*   ei        = (const int*)d_in[1];
  const float* edge_attr = (const float*)d_in[2];
  const float* w_w       = (const float*)d_in[3];
  const float* w_b       = (const float*)d_in[4];
  const float* a_w       = (const float*)d_in[5];
  const float* a_b       = (const float*)d_in[6];
  const int n_nodes = in_sizes[0] / IN_DIM;
  const int nedges  = in_sizes[1] / 2;
  const int nb   = (n_nodes + RPB - 1) / RPB;   // 782
  const int nebl = (nedges + EPB - 1) / EPB;    // 391

  // Workspace (~36 MB): wh | entA (nb*CAP) | gcur | s_row | s_col
  __half* wh       = (__half*)d_ws;                           // n*64 fp16
  int2*  entA      = (int2*)(wh + (size_t)n_nodes * OUT_DIM); // nb*CAP
  int*   gcur      = (int*)(entA + (size_t)nb * CAP);         // MAXB
  float* s_row     = (float*)(gcur + MAXB);                   // n
  float* s_col     = s_row + n_nodes;                         // n

  k_zero<<<1, 256, 0, stream>>>(gcur);
  k_whfill<<<nebl + NWH, 512, 0, stream>>>(h, w_w, w_b, a_w, ei, edge_attr,
                                           wh, s_row, s_col, gcur, entA,
                                           n_nodes, nedges, nb, nebl);
  k_sagg<<<nb, 512, 0, stream>>>(entA, gcur, wh, s_row, s_col, a_b,
                                 (float*)d_out, n_nodes);
}

// Round 10
// 220.768 us; speedup vs baseline: 4.0247x; 1.0139x over previous
//
#include <hip/hip_runtime.h>
#include <hip/hip_fp16.h>

#define IN_DIM 128
#define OUT_DIM 64
#define RPB 128          // rows per bucket (in-LDS sort+agg)
#define MAXB 800         // max buckets  (n_nodes <= 102400)
#define EPB 4096         // edges per block in fill part (512 thr x 8)
#define ENTL 2304        // LDS entry cap per bucket (mean 2048 + >5 sigma)
#define CAP 3584         // per-bucket entA region capacity (mean 3180 + 6 sigma)
#define NWH 320          // wh-part blocks (8 waves each = 2560 wave-slots)

typedef __attribute__((ext_vector_type(8))) _Float16 half8;
typedef __attribute__((ext_vector_type(4))) float f32x4;

// Tiny prologue: zero the per-bucket allocation cursors. Must be a separate
// launch (fill blocks may not assume any cross-block dispatch ordering).
__global__ __launch_bounds__(256) void k_zero(int* __restrict__ gcur) {
  for (int i = threadIdx.x; i < MAXB; i += 256) gcur[i] = 0;
}

// Fat kernel: blocks [0,nfill) = fill body, blocks [nfill,nfill+NWH) = wh
// body. The two are data-independent (fill: ei/edge_attr -> entA; wh:
// h/weights -> wh/s_row/s_col) and stress different pipes, so they
// co-schedule instead of serializing as two launches.
__global__ __launch_bounds__(512) void k_whfill(
    const float* __restrict__ h, const float* __restrict__ w_w,
    const float* __restrict__ w_b, const float* __restrict__ a_w,
    const int* __restrict__ ei, const float* __restrict__ edge_attr,
    __half* __restrict__ wh, float* __restrict__ s_row,
    float* __restrict__ s_col, int* __restrict__ gcur,
    int2* __restrict__ entA, int n_nodes, int nedges, int nb, int nfill) {
  if ((int)blockIdx.x < nfill) {
    // ---------------- fill body ----------------
    __shared__ int hist[MAXB];   // this block's per-bucket count
    __shared__ int cbase[MAXB];  // this block's chunk base (absolute)
    __shared__ int curs[MAXB];   // scatter cursor
    for (int b = threadIdx.x; b < MAXB; b += 512) hist[b] = 0;
    const float aw0 = a_w[128], aw1 = a_w[129], aw2 = a_w[130], aw3 = a_w[131];
    const float aw4 = a_w[132], aw5 = a_w[133], aw6 = a_w[134], aw7 = a_w[135];
    __syncthreads();
    const int e0 = blockIdx.x * EPB;
    int row[8], col[8];
    float s[8];
#pragma unroll
    for (int k = 0; k < 8; ++k) {
      int e = e0 + k * 512 + threadIdx.x;
      if (e < nedges) {
        row[k] = ei[e];
        col[k] = ei[nedges + e];
      } else {
        row[k] = -1;
        col[k] = 0;
      }
    }
#pragma unroll
    for (int k = 0; k < 8; ++k) {
      int e = e0 + k * 512 + threadIdx.x;
      if (row[k] >= 0) {
        const float4* ea = (const float4*)(edge_attr + (size_t)e * 8);
        float4 u = ea[0], v = ea[1];
        float t = u.x * aw0 + u.y * aw1 + u.z * aw2 + u.w * aw3;
        t += v.x * aw4 + v.y * aw5 + v.z * aw6 + v.w * aw7;
        s[k] = t;
      } else {
        s[k] = 0.f;
      }
    }
#pragma unroll
    for (int k = 0; k < 8; ++k)
      if (row[k] >= 0) atomicAdd(&hist[row[k] >> 7], 1);
    __syncthreads();
    for (int b = threadIdx.x; b < nb; b += 512) {
      int c = hist[b];
      int cb = 0;
      if (c > 0) cb = b * CAP + atomicAdd(&gcur[b], (c + 7) & ~7);
      cbase[b] = cb;
      curs[b] = cb;
    }
    __syncthreads();
#pragma unroll
    for (int k = 0; k < 8; ++k) {
      if (row[k] >= 0) {
        int bb = row[k] >> 7;
        int pos = atomicAdd(&curs[bb], 1);
        entA[pos] = make_int2(((row[k] & 127) << 17) | col[k],
                              __float_as_int(s[k]));
      }
    }
    __syncthreads();
    for (int b = threadIdx.x; b < nb; b += 512) {
      int c = hist[b];
      if (c > 0) {
        int st = cbase[b] + c, end = cbase[b] + ((c + 7) & ~7);
        for (int k = st; k < end; ++k) entA[k] = make_int2(-1, 0);
      }
    }
  } else {
    // ---------------- wh body (MFMA, 8 waves per block) ----------------
    __shared__ _Float16 wf[4 * 4 * 64 * 8];
    for (int idx = threadIdx.x; idx < IN_DIM * OUT_DIM; idx += 512) {
      int k = idx >> 6, c = idx & 63;            // w_w[k][c], coalesced read
      int mt = c >> 4;
      int kt = k >> 5;
      int l = (((k >> 3) & 3) << 4) | (c & 15);  // lane owning this (k,c)
      int j = k & 7;
      wf[(((mt << 2) | kt) << 9) | (l << 3) | j] = (_Float16)w_w[idx];
    }
    __syncthreads();

    const int lane = threadIdx.x & 63;
    const int wv = threadIdx.x >> 6;            // 0..7

    half8 A[4][4];
#pragma unroll
    for (int mt = 0; mt < 4; ++mt)
#pragma unroll
      for (int kt = 0; kt < 4; ++kt)
        A[mt][kt] =
            *(const half8*)&wf[(((mt << 2) | kt) << 9) | (lane << 3)];

    const int cbase2 = (lane >> 4) << 2;
    f32x4 bq[4], a1q[4], a2q[4];
#pragma unroll
    for (int mt = 0; mt < 4; ++mt) {
      bq[mt] = *(const f32x4*)&w_b[mt * 16 + cbase2];
      a1q[mt] = *(const f32x4*)&a_w[mt * 16 + cbase2];
      a2q[mt] = *(const f32x4*)&a_w[OUT_DIM + mt * 16 + cbase2];
    }

    const int wb = blockIdx.x - nfill;
    const int ntiles = (n_nodes + 15) >> 4;
    const int tstride = NWH * 8;
    for (int t = wb * 8 + wv; t < ntiles; t += tstride) {
      const int n0 = t << 4;
      const int node = n0 + (lane & 15);
      const int nodec = node < n_nodes ? node : n_nodes - 1;
      const float4* hv =
          (const float4*)(h + (size_t)nodec * IN_DIM + ((lane >> 4) << 3));
      float4 p[8];
#pragma unroll
      for (int kt = 0; kt < 4; ++kt) {
        p[2 * kt] = hv[kt * 8];
        p[2 * kt + 1] = hv[kt * 8 + 1];
      }
      f32x4 C[4];
#pragma unroll
      for (int mt = 0; mt < 4; ++mt) C[mt] = (f32x4){0.f, 0.f, 0.f, 0.f};
#pragma unroll
      for (int kt = 0; kt < 4; ++kt) {
        const float4 u = p[2 * kt], v = p[2 * kt + 1];
        half8 B;
        B[0] = (_Float16)u.x; B[1] = (_Float16)u.y;
        B[2] = (_Float16)u.z; B[3] = (_Float16)u.w;
        B[4] = (_Float16)v.x; B[5] = (_Float16)v.y;
        B[6] = (_Float16)v.z; B[7] = (_Float16)v.w;
#pragma unroll
        for (int mt = 0; mt < 4; ++mt)
          C[mt] = __builtin_amdgcn_mfma_f32_16x16x32_f16(A[mt][kt], B, C[mt],
                                                         0, 0, 0);
      }
      float sr = 0.f, sc = 0.f;
      uint2 q[4];
#pragma unroll
      for (int mt = 0; mt < 4; ++mt) {
        f32x4 d = C[mt] + bq[mt];
        sr += d[0] * a1q[mt][0] + d[1] * a1q[mt][1] + d[2] * a1q[mt][2] +
              d[3] * a1q[mt][3];
        sc += d[0] * a2q[mt][0] + d[1] * a2q[mt][1] + d[2] * a2q[mt][2] +
              d[3] * a2q[mt][3];
        __half2 lo = __floats2half2_rn(d[0], d[1]);
        __half2 hi = __floats2half2_rn(d[2], d[3]);
        q[mt].x = *(unsigned int*)&lo;
        q[mt].y = *(unsigned int*)&hi;
      }
      if (node < n_nodes) {
        uint2* wrow = (uint2*)(wh + (size_t)node * OUT_DIM + cbase2);
        wrow[0] = q[0];
        wrow[4] = q[1];
        wrow[8] = q[2];
        wrow[12] = q[3];
      }
      sr += __shfl_xor(sr, 16, 64);
      sr += __shfl_xor(sr, 32, 64);
      sc += __shfl_xor(sc, 16, 64);
      sc += __shfl_xor(sc, 32, 64);
      if (lane < 16 && node < n_nodes) {
        s_row[node] = sr;
        s_col[node] = sc;
      }
    }
  }
}

// Phase 3 (fused sort+agg): one block per 128-row bucket. Stage bucket
// entries in registers, LDS-histogram rows, scan -> per-row starts,
// scatter row-sorted into LDS, then pull-agg per node.
// Agg loop is 4-deep (8 slots x 8 lanes, 32 edges of MLP per iteration):
// k_sagg is gather-latency-bound (R9: 1.87 TB/s == Little's-law limit at
// 2-deep), so double the in-flight wh gathers per thread.
__global__ __launch_bounds__(512) void k_sagg(
    const int2* __restrict__ entA, const int* __restrict__ gcur,
    const __half* __restrict__ wh,
    const float* __restrict__ s_row, const float* __restrict__ s_col,
    const float* __restrict__ a_b, float* __restrict__ out, int n_nodes) {
  __shared__ int2 entl[ENTL];
  __shared__ int hist[RPB], sd[RPB], starts[RPB], curs[RPB], degs[RPB];
  const int b = blockIdx.x;
  const int row0 = b << 7;
  const int t = threadIdx.x;
  if (t < RPB) hist[t] = 0;
  __syncthreads();
  const int c = gcur[b];       // padded count (sentinels included)
  const int base = b * CAP;
  // --- stage + histogram ---
  int2 e[8];
#pragma unroll
  for (int k = 0; k < 8; ++k) {
    int i = t + k * 512;
    e[k] = (i < c) ? entA[base + i] : make_int2(-1, 0);
  }
#pragma unroll
  for (int k = 0; k < 8; ++k)
    if (e[k].x >= 0) atomicAdd(&hist[e[k].x >> 17], 1);
  for (int i = t + 4096; i < c; i += 512) {  // overflow guard (never runs)
    int2 p = entA[base + i];
    if (p.x >= 0) atomicAdd(&hist[p.x >> 17], 1);
  }
  __syncthreads();
  // --- scan hist[128] ---
  int hh = 0;
  if (t < RPB) { hh = hist[t]; sd[t] = hh; }
  __syncthreads();
  for (int off = 1; off < RPB; off <<= 1) {
    int x = (t >= off && t < RPB) ? sd[t - off] : 0;
    __syncthreads();
    if (t < RPB) sd[t] += x;
    __syncthreads();
  }
  if (t < RPB) {
    int excl = sd[t] - hh;
    starts[t] = excl;
    curs[t] = excl;
    degs[t] = hh;
  }
  __syncthreads();
  // --- scatter row-sorted into LDS ---
#pragma unroll
  for (int k = 0; k < 8; ++k)
    if (e[k].x >= 0) {
      int p = atomicAdd(&curs[e[k].x >> 17], 1);
      if (p < ENTL) entl[p] = e[k];
    }
  for (int i = t + 4096; i < c; i += 512) {  // overflow guard (never runs)
    int2 p2 = entA[base + i];
    if (p2.x >= 0) {
      int p = atomicAdd(&curs[p2.x >> 17], 1);
      if (p < ENTL) entl[p] = p2;
    }
  }
  __syncthreads();
  // --- aggregate: 8 waves x 16 nodes each, 4 edges/thread in flight ---
  const int wv = t >> 6;
  const int lane = t & 63;
  const int slot = lane >> 3, sub = lane & 7;
  const float ab = a_b[0];
  const uint4* whq = (const uint4*)wh;
  for (int j = 0; j < 16; ++j) {
    const int rl = wv * 16 + j;
    const int node = row0 + rl;
    if (node >= n_nodes) break;
    const int st = starts[rl];
    const int dg = degs[rl];
    const float sab = s_row[node] + ab;
    float acc[8] = {0.f, 0.f, 0.f, 0.f, 0.f, 0.f, 0.f, 0.f};
    float l = 0.f;
    for (int bas = 0; bas < dg; bas += 32) {
      const int i0 = bas + slot, i1 = i0 + 8, i2 = i0 + 16, i3 = i0 + 24;
      const bool g0 = i0 < dg, g1 = i1 < dg, g2 = i2 < dg, g3 = i3 < dg;
      int2 p0 = g0 ? entl[st + i0] : make_int2(0, 0);
      int2 p1 = g1 ? entl[st + i1] : make_int2(0, 0);
      int2 p2 = g2 ? entl[st + i2] : make_int2(0, 0);
      int2 p3 = g3 ? entl[st + i3] : make_int2(0, 0);
      const int col0 = p0.x & 0x1FFFF, col1 = p1.x & 0x1FFFF;
      const int col2 = p2.x & 0x1FFFF, col3 = p3.x & 0x1FFFF;
      uint4 q0 = make_uint4(0, 0, 0, 0), q1 = make_uint4(0, 0, 0, 0);
      uint4 q2 = make_uint4(0, 0, 0, 0), q3 = make_uint4(0, 0, 0, 0);
      float sc0 = 0.f, sc1 = 0.f, sc2 = 0.f, sc3 = 0.f;
      if (g0) { q0 = whq[(size_t)col0 * 8 + sub]; sc0 = s_col[col0]; }
      if (g1) { q1 = whq[(size_t)col1 * 8 + sub]; sc1 = s_col[col1]; }
      if (g2) { q2 = whq[(size_t)col2 * 8 + sub]; sc2 = s_col[col2]; }
      if (g3) { q3 = whq[(size_t)col3 * 8 + sub]; sc3 = s_col[col3]; }
      if (g0) {
        float s = sab + sc0 + __int_as_float(p0.y);
        float ev = (s > 0.f) ? s : 0.01f * s;  // leaky_relu
        float a = __expf(ev);  // softmax shift-invariance: no segment max
        float2 f0 = __half22float2(*(__half2*)&q0.x);
        float2 f1 = __half22float2(*(__half2*)&q0.y);
        float2 f2 = __half22float2(*(__half2*)&q0.z);
        float2 f3 = __half22float2(*(__half2*)&q0.w);
        acc[0] = fmaf(a, f0.x, acc[0]); acc[1] = fmaf(a, f0.y, acc[1]);
        acc[2] = fmaf(a, f1.x, acc[2]); acc[3] = fmaf(a, f1.y, acc[3]);
        acc[4] = fmaf(a, f2.x, acc[4]); acc[5] = fmaf(a, f2.y, acc[5]);
        acc[6] = fmaf(a, f3.x, acc[6]); acc[7] = fmaf(a, f3.y, acc[7]);
        if (sub == 0) l += a;
      }
      if (g1) {
        float s = sab + sc1 + __int_as_float(p1.y);
        float ev = (s > 0.f) ? s : 0.01f * s;
        float a = __expf(ev);
        float2 f0 = __half22float2(*(__half2*)&q1.x);
        float2 f1 = __half22float2(*(__half2*)&q1.y);
        float2 f2 = __half22float2(*(__half2*)&q1.z);
        float2 f3 = __half22float2(*(__half2*)&q1.w);
        acc[0] = fmaf(a, f0.x, acc[0]); acc[1] = fmaf(a, f0.y, acc[1]);
        acc[2] = fmaf(a, f1.x, acc[2]); acc[3] = fmaf(a, f1.y, acc[3]);
        acc[4] = fmaf(a, f2.x, acc[4]); acc[5] = fmaf(a, f2.y, acc[5]);
        acc[6] = fmaf(a, f3.x, acc[6]); acc[7] = fmaf(a, f3.y, acc[7]);
        if (sub == 0) l += a;
      }
      if (g2) {
        float s = sab + sc2 + __int_as_float(p2.y);
        float ev = (s > 0.f) ? s : 0.01f * s;
        float a = __expf(ev);
        float2 f0 = __half22float2(*(__half2*)&q2.x);
        float2 f1 = __half22float2(*(__half2*)&q2.y);
        float2 f2 = __half22float2(*(__half2*)&q2.z);
        float2 f3 = __half22float2(*(__half2*)&q2.w);
        acc[0] = fmaf(a, f0.x, acc[0]); acc[1] = fmaf(a, f0.y, acc[1]);
        acc[2] = fmaf(a, f1.x, acc[2]); acc[3] = fmaf(a, f1.y, acc[3]);
        acc[4] = fmaf(a, f2.x, acc[4]); acc[5] = fmaf(a, f2.y, acc[5]);
        acc[6] = fmaf(a, f3.x, acc[6]); acc[7] = fmaf(a, f3.y, acc[7]);
        if (sub == 0) l += a;
      }
      if (g3) {
        float s = sab + sc3 + __int_as_float(p3.y);
        float ev = (s > 0.f) ? s : 0.01f * s;
        float a = __expf(ev);
        float2 f0 = __half22float2(*(__half2*)&q3.x);
        float2 f1 = __half22float2(*(__half2*)&q3.y);
        float2 f2 = __half22float2(*(__half2*)&q3.z);
        float2 f3 = __half22float2(*(__half2*)&q3.w);
        acc[0] = fmaf(a, f0.x, acc[0]); acc[1] = fmaf(a, f0.y, acc[1]);
        acc[2] = fmaf(a, f1.x, acc[2]); acc[3] = fmaf(a, f1.y, acc[3]);
        acc[4] = fmaf(a, f2.x, acc[4]); acc[5] = fmaf(a, f2.y, acc[5]);
        acc[6] = fmaf(a, f3.x, acc[6]); acc[7] = fmaf(a, f3.y, acc[7]);
        if (sub == 0) l += a;
      }
    }
#pragma unroll
    for (int d = 0; d < 8; ++d) {
      acc[d] += __shfl_xor(acc[d], 8, 64);
      acc[d] += __shfl_xor(acc[d], 16, 64);
      acc[d] += __shfl_xor(acc[d], 32, 64);
    }
    l += __shfl_xor(l, 8, 64);
    l += __shfl_xor(l, 16, 64);
    l += __shfl_xor(l, 32, 64);
    float lt = __shfl(l, 0, 64);
    if (slot == 0) {
      float inv = 1.0f / (lt + 1e-8f);
      float4 o0 = make_float4(acc[0] * inv, acc[1] * inv, acc[2] * inv,
                              acc[3] * inv);
      float4 o1 = make_float4(acc[4] * inv, acc[5] * inv, acc[6] * inv,
                              acc[7] * inv);
      float4* orow = (float4*)out + (size_t)node * 16 + sub * 2;
      orow[0] = o0;
      orow[1] = o1;
    }
  }
}

extern "C" void kernel_launch(void* const* d_in, const int* in_sizes, int n_in,
                              void* d_out, int out_size, void* d_ws, size_t ws_size,
                              hipStream_t stream) {
  const float* h         = (const float*)d_in[0];
  const int*   ei        = (const int*)d_in[1];
  const float* edge_attr = (const float*)d_in[2];
  const float* w_w       = (const float*)d_in[3];
  const float* w_b       = (const float*)d_in[4];
  const float* a_w       = (const float*)d_in[5];
  const float* a_b       = (const float*)d_in[6];
  const int n_nodes = in_sizes[0] / IN_DIM;
  const int nedges  = in_sizes[1] / 2;
  const int nb   = (n_nodes + RPB - 1) / RPB;   // 782
  const int nebl = (nedges + EPB - 1) / EPB;    // 391

  // Workspace (~36 MB): wh | entA (nb*CAP) | gcur | s_row | s_col
  __half* wh       = (__half*)d_ws;                           // n*64 fp16
  int2*  entA      = (int2*)(wh + (size_t)n_nodes * OUT_DIM); // nb*CAP
  int*   gcur      = (int*)(entA + (size_t)nb * CAP);         // MAXB
  float* s_row     = (float*)(gcur + MAXB);                   // n
  float* s_col     = s_row + n_nodes;                         // n

  k_zero<<<1, 256, 0, stream>>>(gcur);
  k_whfill<<<nebl + NWH, 512, 0, stream>>>(h, w_w, w_b, a_w, ei, edge_attr,
                                           wh, s_row, s_col, gcur, entA,
                                           n_nodes, nedges, nb, nebl);
  k_sagg<<<nb, 512, 0, stream>>>(entA, gcur, wh, s_row, s_col, a_b,
                                 (float*)d_out, n_nodes);
}